// Round 12
// baseline (127.612 us; speedup 1.0000x reference)
//
#include <hip/hip_runtime.h>

#define Dq   256
#define ATTR 400
#define HW   3136
#define NB   32

typedef __attribute__((ext_vector_type(8))) short bf16x8;
typedef __attribute__((ext_vector_type(4))) float f32x4;

__device__ __forceinline__ unsigned short f2bf(float f) {
  unsigned int x = __float_as_uint(f);
  return (unsigned short)((x + 0x7FFFu + ((x >> 16) & 1u)) >> 16);
}

// ---------------- Kernel A: per-batch count-sketch vector sk1[b][256] ----------------
__global__ __launch_bounds__(256) void k_sk1(
    const float* __restrict__ oh, const float* __restrict__ W_emb,
    const float* __restrict__ b_emb, const float* __restrict__ conv_w,
    const float* __restrict__ conv_b, const int* __restrict__ h1,
    const float* __restrict__ s1, float* __restrict__ sk1_out) {
  __shared__ float ohs[ATTR];
  __shared__ float ts[Dq];
  __shared__ float sk[Dq];
  const int b = blockIdx.x, tid = threadIdx.x;
  for (int j = tid; j < ATTR; j += 256) ohs[j] = oh[b * ATTR + j];
  sk[tid] = 0.f;
  __syncthreads();
  float acc = b_emb[tid];
  const float* wr = W_emb + tid * ATTR;
  for (int j = 0; j < ATTR; ++j) acc = fmaf(ohs[j], wr[j], acc);
  ts[tid] = acc;
  __syncthreads();
  float a = conv_b[tid];
  const float* cr = conv_w + tid * Dq;
  for (int k = 0; k < Dq; ++k) a = fmaf(ts[k], cr[k], a);
  atomicAdd(&sk[h1[tid]], a * s1[tid]);
  __syncthreads();
  sk1_out[b * Dq + tid] = sk[tid];
}

// ---------------- Kernel B: circular conv + scatter straight into MFMA A-fragment layout ----------------
// Block (b,o). thread tid = c. Writes Abuf[b][frag][lane][j] (bf16) where
// A[m=o][k=c] = G[b][c][o] = s2[c] * T[o,h2[c]]:
//   frag = (o>>4)*8 + (c>>5), lane = (o&15) | (((c>>3)&3)<<4), j = c&7.
__global__ __launch_bounds__(256) void k_G(
    const float* __restrict__ sk1, const float* __restrict__ conv1_w,
    const int* __restrict__ h2, const float* __restrict__ s2,
    unsigned short* __restrict__ Abuf) {
  __shared__ float sks[Dq];
  __shared__ float w1[Dq];
  __shared__ float Tl[Dq];
  const int b = blockIdx.x >> 5, o = blockIdx.x & 31, c = threadIdx.x;
  sks[c] = sk1[b * Dq + c];
  w1[c]  = conv1_w[o * Dq + c];
  __syncthreads();
  float t = 0.f;
  for (int d = 0; d < Dq; ++d) t = fmaf(w1[d], sks[(d - c) & 255], t);
  Tl[c] = t;
  __syncthreads();
  const float g = s2[c] * Tl[h2[c]];
  const int frag = (o >> 4) * 8 + (c >> 5);
  const int lane = (o & 15) | (((c >> 3) & 3) << 4);
  Abuf[(((size_t)b * 16 + frag) * 64 + lane) * 8 + (c & 7)] = f2bf(g);
}

// ---------------- Fused kernel v4: split-K across 4 waves, float4 loads ----------------
// Block = 4 waves x 64 lanes, 64 pixels x 256 channels. Wave w owns channels
// [w*64, w*64+64) = global k-steps {2w, 2w+1}. Lane l: n=l&15 (pixel group
// 4n..4n+3), kg=l>>4. MFMA q handles pixels 4n+q. Cross-wave reduce via
// 8KB LDS ds_add_f32 at [reg][lane] (conflict-free). Epilogue computed
// redundantly per wave (each needs s4 for its store phase). Phase 2:
// per-wave re-read of its own 64 channels (L2-hot) + cached float4 stores.
__global__ __launch_bounds__(256) void k_fused(
    const float* __restrict__ ent,            // [B,256,HW]
    const unsigned short* __restrict__ Abuf,  // [B,16,64,8]
    const float* __restrict__ c1b, const float* __restrict__ c2w,
    const float* __restrict__ c2b,
    float* __restrict__ out)                  // map [B,HW] then feat [B,256,HW]
{
  __shared__ float red[32][64];               // [reg][lane], 8 KB
  const int b = blockIdx.y, tid = threadIdx.x;
  const int w = tid >> 6, l = tid & 63;
  const int n = l & 15, kg = l >> 4;
  const int px_base = blockIdx.x * 64;        // 49*64 = 3136 exact

  for (int i = tid; i < 2048; i += 256) (&red[0][0])[i] = 0.f;

  const float* ep = ent + (size_t)b * Dq * HW + px_base + 4 * n;
  const unsigned short* Ab = Abuf + ((size_t)b * 16 * 64 + l) * 8;

  f32x4 acc[4][2];
#pragma unroll
  for (int q = 0; q < 4; ++q) { acc[q][0] = f32x4{0,0,0,0}; acc[q][1] = f32x4{0,0,0,0}; }

  __syncthreads();  // red zeroed before any atomics

#pragma unroll
  for (int ks = 0; ks < 2; ++ks) {
    const int ksg = w * 2 + ks;               // global k-step 0..7
    f32x4 f[8];
#pragma unroll
    for (int j = 0; j < 8; ++j)
      f[j] = *reinterpret_cast<const f32x4*>(ep + (size_t)(ksg * 32 + kg * 8 + j) * HW);

    bf16x8 a0 = *reinterpret_cast<const bf16x8*>(Ab + (size_t)(0 * 8 + ksg) * 64 * 8);
    bf16x8 a1 = *reinterpret_cast<const bf16x8*>(Ab + (size_t)(1 * 8 + ksg) * 64 * 8);

#pragma unroll
    for (int q = 0; q < 4; ++q) {
      bf16x8 bv;
#pragma unroll
      for (int j = 0; j < 8; ++j) bv[j] = (short)f2bf(fmaxf(f[j][q], 0.f));
      acc[q][0] = __builtin_amdgcn_mfma_f32_16x16x32_bf16(a0, bv, acc[q][0], 0, 0, 0);
      acc[q][1] = __builtin_amdgcn_mfma_f32_16x16x32_bf16(a1, bv, acc[q][1], 0, 0, 0);
    }
  }

  // cross-wave reduce: acc[q][t][r] is a[o = t*16+kg*4+r][px = 4n+q] partial
#pragma unroll
  for (int q = 0; q < 4; ++q)
#pragma unroll
    for (int t = 0; t < 2; ++t)
#pragma unroll
      for (int r = 0; r < 4; ++r)
        atomicAdd(&red[q * 8 + t * 4 + r][l], acc[q][t][r]);
  __syncthreads();

  // epilogue (redundant per wave): o = kg*4+r (tile0), +16 (tile1)
  const float4 b1a = reinterpret_cast<const float4*>(c1b)[kg];
  const float4 b1b = reinterpret_cast<const float4*>(c1b)[kg + 4];
  const float4 w2a = reinterpret_cast<const float4*>(c2w)[kg];
  const float4 w2b = reinterpret_cast<const float4*>(c2w)[kg + 4];
  const float c2b0 = c2b[0];

  f32x4 s4;
#pragma unroll
  for (int q = 0; q < 4; ++q) {
    float z = 0.f;
    z = fmaf(w2a.x, fmaxf(red[q * 8 + 0][l] + b1a.x, 0.f), z);
    z = fmaf(w2a.y, fmaxf(red[q * 8 + 1][l] + b1a.y, 0.f), z);
    z = fmaf(w2a.z, fmaxf(red[q * 8 + 2][l] + b1a.z, 0.f), z);
    z = fmaf(w2a.w, fmaxf(red[q * 8 + 3][l] + b1a.w, 0.f), z);
    z = fmaf(w2b.x, fmaxf(red[q * 8 + 4][l] + b1b.x, 0.f), z);
    z = fmaf(w2b.y, fmaxf(red[q * 8 + 5][l] + b1b.y, 0.f), z);
    z = fmaf(w2b.z, fmaxf(red[q * 8 + 6][l] + b1b.z, 0.f), z);
    z = fmaf(w2b.w, fmaxf(red[q * 8 + 7][l] + b1b.w, 0.f), z);
    z += __shfl_xor(z, 16);                   // sum over kg
    z += __shfl_xor(z, 32);
    s4[q] = 1.f / (1.f + __expf(-(z + c2b0)));
  }

  // attr_map: wave 0, lanes 0..15 (n = l) store float4 each
  if (tid < 16)
    *reinterpret_cast<f32x4*>(out + (size_t)b * HW + px_base + 4 * l) = s4;

  // ---- phase 2: wave w re-reads/stores its own 64 channels (L2-hot) ----
  const size_t fb = (size_t)NB * HW + (size_t)b * Dq * HW + px_base + 4 * n;
  float* fp = out + fb;
#pragma unroll 4
  for (int cc = 0; cc < 16; ++cc) {
    const size_t off = (size_t)(w * 64 + kg * 16 + cc) * HW;
    f32x4 e = *reinterpret_cast<const f32x4*>(ep + off);
    *reinterpret_cast<f32x4*>(fp + off) = e * s4;
  }
}

extern "C" void kernel_launch(void* const* d_in, const int* in_sizes, int n_in,
                              void* d_out, int out_size, void* d_ws, size_t ws_size,
                              hipStream_t stream) {
  const float* ent    = (const float*)d_in[0];
  const float* oh     = (const float*)d_in[1];
  const float* W_emb  = (const float*)d_in[2];
  const float* b_emb  = (const float*)d_in[3];
  const float* conv_w = (const float*)d_in[4];
  const float* conv_b = (const float*)d_in[5];
  const float* c1w    = (const float*)d_in[6];
  const float* c1b    = (const float*)d_in[7];
  const float* c2w    = (const float*)d_in[8];
  const float* c2b    = (const float*)d_in[9];
  const int*   h1     = (const int*)d_in[10];
  const int*   h2     = (const int*)d_in[11];
  const float* s1     = (const float*)d_in[12];
  const float* s2     = (const float*)d_in[13];

  float* ws  = (float*)d_ws;
  float* sk1 = ws;                                        // 32*256 f32
  unsigned short* Abuf = (unsigned short*)(ws + NB * Dq); // 32*16*64*8 bf16

  hipLaunchKernelGGL(k_sk1, dim3(NB), dim3(256), 0, stream,
                     oh, W_emb, b_emb, conv_w, conv_b, h1, s1, sk1);
  hipLaunchKernelGGL(k_G, dim3(NB * 32), dim3(256), 0, stream,
                     sk1, c1w, h2, s2, Abuf);
  hipLaunchKernelGGL(k_fused, dim3(HW / 64, NB), dim3(256), 0, stream,
                     ent, Abuf, c1b, c2w, c2b, (float*)d_out);
}

// Round 13
// 70.312 us; speedup vs baseline: 1.8150x; 1.8150x over previous
//
#include <hip/hip_runtime.h>

#define Dq    256
#define ATTR  400
#define HW    3136
#define NB    32
#define PXT   112     // pixel tile per block
#define NPX4  28      // PXT/4
#define PITCH 116     // LDS row pitch (bf16 elements): 232B rows -> conflict-light
#define NTILE 28      // HW/PXT

typedef __attribute__((ext_vector_type(8))) short bf16x8;
typedef __attribute__((ext_vector_type(4))) float f32x4;

__device__ __forceinline__ unsigned short f2bf(float f) {
  unsigned int x = __float_as_uint(f);
  return (unsigned short)((x + 0x7FFFu + ((x >> 16) & 1u)) >> 16);
}
__device__ __forceinline__ float bf2f(unsigned int u) {
  return __uint_as_float(u << 16);
}

// ---------------- Kernel A: per-batch count-sketch vector sk1[b][256] ----------------
__global__ __launch_bounds__(256) void k_sk1(
    const float* __restrict__ oh, const float* __restrict__ W_emb,
    const float* __restrict__ b_emb, const float* __restrict__ conv_w,
    const float* __restrict__ conv_b, const int* __restrict__ h1,
    const float* __restrict__ s1, float* __restrict__ sk1_out) {
  __shared__ float ohs[ATTR];
  __shared__ float ts[Dq];
  __shared__ float sk[Dq];
  const int b = blockIdx.x, tid = threadIdx.x;
  for (int j = tid; j < ATTR; j += 256) ohs[j] = oh[b * ATTR + j];
  sk[tid] = 0.f;
  __syncthreads();
  float acc = b_emb[tid];
  const float* wr = W_emb + tid * ATTR;
  for (int j = 0; j < ATTR; ++j) acc = fmaf(ohs[j], wr[j], acc);
  ts[tid] = acc;
  __syncthreads();
  float a = conv_b[tid];
  const float* cr = conv_w + tid * Dq;
  for (int k = 0; k < Dq; ++k) a = fmaf(ts[k], cr[k], a);
  atomicAdd(&sk[h1[tid]], a * s1[tid]);
  __syncthreads();
  sk1_out[b * Dq + tid] = sk[tid];
}

// ---------------- Kernel B: circular conv + scatter into MFMA A-fragment layout ----------------
// A[m=o][k=c] = G[b][c][o] = s2[c] * T[o,h2[c]]:
//   frag = (o>>4)*8 + (c>>5), lane = (o&15) | (((c>>3)&3)<<4), j = c&7.
__global__ __launch_bounds__(256) void k_G(
    const float* __restrict__ sk1, const float* __restrict__ conv1_w,
    const int* __restrict__ h2, const float* __restrict__ s2,
    unsigned short* __restrict__ Abuf) {
  __shared__ float sks[Dq];
  __shared__ float w1[Dq];
  __shared__ float Tl[Dq];
  const int b = blockIdx.x >> 5, o = blockIdx.x & 31, c = threadIdx.x;
  sks[c] = sk1[b * Dq + c];
  w1[c]  = conv1_w[o * Dq + c];
  __syncthreads();
  float t = 0.f;
  for (int d = 0; d < Dq; ++d) t = fmaf(w1[d], sks[(d - c) & 255], t);
  Tl[c] = t;
  __syncthreads();
  const float g = s2[c] * Tl[h2[c]];
  const int frag = (o >> 4) * 8 + (c >> 5);
  const int lane = (o & 15) | (((c >> 3) & 3) << 4);
  Abuf[(((size_t)b * 16 + frag) * 64 + lane) * 8 + (c & 7)] = f2bf(g);
}

// ---------------- Kernel TILE: stage -> gate (MFMA from LDS) -> store ----------------
// Block = 448 thr (7 waves), tile [256 ch][112 px], LDS bf16 [256][PITCH=116].
// Stage: 16 independent f32x4 loads/thread (448B-contiguous chunks), cvt bf16,
// ds_write_b64. Gate: wave w = px-subtile w (16 px); bv gathered as 8 u16
// from LDS; MFMA vs resident-in-L2 Abuf; per-lane sigmoid after shfl reduce.
// Store: same thread mapping as stage; read LDS tile, multiply by s, f32x4
// contiguous global stores. Entity touched exactly once in global memory.
__global__ __launch_bounds__(448, 4) void k_tile(
    const float* __restrict__ ent,            // [B,256,HW]
    const unsigned short* __restrict__ Abuf,  // [B,16,64,8]
    const float* __restrict__ c1b, const float* __restrict__ c2w,
    const float* __restrict__ c2b,
    float* __restrict__ out)                  // map [B,HW] then feat [B,256,HW]
{
  __shared__ unsigned short tile[Dq * PITCH]; // 59,392 B
  __shared__ float s_lds[PXT];
  const int b = blockIdx.y;
  const int px_base = blockIdx.x * PXT;       // 28*112 = 3136 exact
  const int t = threadIdx.x;
  const int c0 = t / NPX4;                    // 0..15
  const int fi = t % NPX4;                    // 0..27 (float4 index in row)

  const float* eb = ent + (size_t)b * Dq * HW + px_base;

  // ---- stage: 16 independent float4 loads, cvt, LDS write ----
#pragma unroll
  for (int k = 0; k < 16; ++k) {
    const int c = 16 * k + c0;
    f32x4 v = *reinterpret_cast<const f32x4*>(eb + (size_t)c * HW + 4 * fi);
    unsigned int d0 = (unsigned int)f2bf(v[0]) | ((unsigned int)f2bf(v[1]) << 16);
    unsigned int d1 = (unsigned int)f2bf(v[2]) | ((unsigned int)f2bf(v[3]) << 16);
    uint2 dv; dv.x = d0; dv.y = d1;
    *reinterpret_cast<uint2*>(&tile[c * PITCH + 4 * fi]) = dv;
  }
  __syncthreads();

  // ---- gate: wave w owns px subtile [w*16, w*16+16) ----
  const int w = t >> 6, l = t & 63;
  const int n = l & 15, kg = l >> 4;
  const unsigned short* Ab = Abuf + ((size_t)b * 16 * 64 + l) * 8;

  f32x4 acc0 = {0.f, 0.f, 0.f, 0.f}, acc1 = {0.f, 0.f, 0.f, 0.f};
#pragma unroll
  for (int ks = 0; ks < 8; ++ks) {
    unsigned short uv[8];
#pragma unroll
    for (int j = 0; j < 8; ++j)
      uv[j] = tile[(ks * 32 + kg * 8 + j) * PITCH + w * 16 + n];
    bf16x8 bv;
#pragma unroll
    for (int j = 0; j < 8; ++j)
      bv[j] = (short)((uv[j] & 0x8000u) ? 0u : (unsigned int)uv[j]);  // relu in bf16
    bf16x8 a0 = *reinterpret_cast<const bf16x8*>(Ab + (size_t)(0 * 8 + ks) * 64 * 8);
    bf16x8 a1 = *reinterpret_cast<const bf16x8*>(Ab + (size_t)(1 * 8 + ks) * 64 * 8);
    acc0 = __builtin_amdgcn_mfma_f32_16x16x32_bf16(a0, bv, acc0, 0, 0, 0);
    acc1 = __builtin_amdgcn_mfma_f32_16x16x32_bf16(a1, bv, acc1, 0, 0, 0);
  }

  // epilogue: C/D col(px)=l&15, row(o)=kg*4+reg (+16 tile1)
  const float4 b1a = reinterpret_cast<const float4*>(c1b)[kg];
  const float4 b1b = reinterpret_cast<const float4*>(c1b)[kg + 4];
  const float4 w2a = reinterpret_cast<const float4*>(c2w)[kg];
  const float4 w2b = reinterpret_cast<const float4*>(c2w)[kg + 4];
  float z = 0.f;
  z = fmaf(w2a.x, fmaxf(acc0[0] + b1a.x, 0.f), z);
  z = fmaf(w2a.y, fmaxf(acc0[1] + b1a.y, 0.f), z);
  z = fmaf(w2a.z, fmaxf(acc0[2] + b1a.z, 0.f), z);
  z = fmaf(w2a.w, fmaxf(acc0[3] + b1a.w, 0.f), z);
  z = fmaf(w2b.x, fmaxf(acc1[0] + b1b.x, 0.f), z);
  z = fmaf(w2b.y, fmaxf(acc1[1] + b1b.y, 0.f), z);
  z = fmaf(w2b.z, fmaxf(acc1[2] + b1b.z, 0.f), z);
  z = fmaf(w2b.w, fmaxf(acc1[3] + b1b.w, 0.f), z);
  z += __shfl_xor(z, 16);
  z += __shfl_xor(z, 32);
  const float s = 1.f / (1.f + __expf(-(z + c2b[0])));
  if (l < 16) {
    out[(size_t)b * HW + px_base + w * 16 + l] = s;
    s_lds[w * 16 + l] = s;
  }
  __syncthreads();

  // ---- store: feat = s * e(bf16), same mapping as stage, contiguous f32x4 ----
  const f32x4 s4 = *reinterpret_cast<const f32x4*>(&s_lds[4 * fi]);
  float* fb = out + (size_t)NB * HW + (size_t)b * Dq * HW + px_base;
#pragma unroll
  for (int k = 0; k < 16; ++k) {
    const int c = 16 * k + c0;
    uint2 dv = *reinterpret_cast<const uint2*>(&tile[c * PITCH + 4 * fi]);
    f32x4 r;
    r[0] = bf2f(dv.x & 0xFFFFu) * s4[0];
    r[1] = bf2f(dv.x >> 16)     * s4[1];
    r[2] = bf2f(dv.y & 0xFFFFu) * s4[2];
    r[3] = bf2f(dv.y >> 16)     * s4[3];
    *reinterpret_cast<f32x4*>(fb + (size_t)c * HW + 4 * fi) = r;
  }
}

extern "C" void kernel_launch(void* const* d_in, const int* in_sizes, int n_in,
                              void* d_out, int out_size, void* d_ws, size_t ws_size,
                              hipStream_t stream) {
  const float* ent    = (const float*)d_in[0];
  const float* oh     = (const float*)d_in[1];
  const float* W_emb  = (const float*)d_in[2];
  const float* b_emb  = (const float*)d_in[3];
  const float* conv_w = (const float*)d_in[4];
  const float* conv_b = (const float*)d_in[5];
  const float* c1w    = (const float*)d_in[6];
  const float* c1b    = (const float*)d_in[7];
  const float* c2w    = (const float*)d_in[8];
  const float* c2b    = (const float*)d_in[9];
  const int*   h1     = (const int*)d_in[10];
  const int*   h2     = (const int*)d_in[11];
  const float* s1     = (const float*)d_in[12];
  const float* s2     = (const float*)d_in[13];

  float* ws  = (float*)d_ws;
  float* sk1 = ws;                                        // 32*256 f32
  unsigned short* Abuf = (unsigned short*)(ws + NB * Dq); // 32*16*64*8 bf16

  hipLaunchKernelGGL(k_sk1, dim3(NB), dim3(256), 0, stream,
                     oh, W_emb, b_emb, conv_w, conv_b, h1, s1, sk1);
  hipLaunchKernelGGL(k_G, dim3(NB * 32), dim3(256), 0, stream,
                     sk1, c1w, h2, s2, Abuf);
  hipLaunchKernelGGL(k_tile, dim3(NTILE, NB), dim3(448), 0, stream,
                     ent, Abuf, c1b, c2w, c2b, (float*)d_out);
}